// Round 1
// baseline (534.585 us; speedup 1.0000x reference)
//
#include <hip/hip_runtime.h>

#define VOCAB 10000
#define EMBED 300

// 16-lane sub-groups: each group handles one batch element per iteration.
// Row = 300 floats = 75 float4; lanes 0..15 cover idx = lane + 16k, k=0..4.
__global__ __launch_bounds__(256) void glove_kernel(
    const int* __restrict__ center, const int* __restrict__ context,
    const float* __restrict__ V, const float* __restrict__ U,
    const float* __restrict__ vb, const float* __restrict__ ub,
    const float* __restrict__ comat, float* __restrict__ out, int batch)
{
    const int lane16 = threadIdx.x & 15;
    const int group  = threadIdx.x >> 4;
    const int gpb    = blockDim.x >> 4;
    const int gid    = blockIdx.x * gpb + group;
    const int ngroups = gridDim.x * gpb;

    float total = 0.f;
    for (int b = gid; b < batch; b += ngroups) {
        const int i = center[b];
        const int j = context[b];
        const float4* __restrict__ Vrow = (const float4*)(V + (size_t)i * EMBED);
        const float4* __restrict__ Urow = (const float4*)(U + (size_t)j * EMBED);
        float dot = 0.f;
#pragma unroll
        for (int k = 0; k < 5; ++k) {
            const int idx = lane16 + 16 * k;
            if (idx < 75) {
                float4 a = Vrow[idx];
                float4 c = Urow[idx];
                dot = fmaf(a.x, c.x, dot);
                dot = fmaf(a.y, c.y, dot);
                dot = fmaf(a.z, c.z, dot);
                dot = fmaf(a.w, c.w, dot);
            }
        }
        // reduce within the 16-lane group
#pragma unroll
        for (int off = 8; off > 0; off >>= 1)
            dot += __shfl_down(dot, off, 16);
        if (lane16 == 0) {
            const float x = comat[(size_t)i * VOCAB + j];
            const float w = (x < 100.0f) ? __powf(x * 0.01f, 0.75f) : 1.0f;
            const float r = dot + vb[i] + ub[j] - __logf(x);
            total = fmaf(w * r, r, total);
        }
    }

    // wave-level reduce (width 64), then cross-wave via LDS, one atomic/block
#pragma unroll
    for (int off = 32; off > 0; off >>= 1)
        total += __shfl_down(total, off, 64);

    __shared__ float smem[4];
    const int wave = threadIdx.x >> 6;
    const int lane = threadIdx.x & 63;
    if (lane == 0) smem[wave] = total;
    __syncthreads();
    if (threadIdx.x == 0) {
        float s = smem[0] + smem[1] + smem[2] + smem[3];
        atomicAdd(out, s);
    }
}

extern "C" void kernel_launch(void* const* d_in, const int* in_sizes, int n_in,
                              void* d_out, int out_size, void* d_ws, size_t ws_size,
                              hipStream_t stream) {
    const int*   center  = (const int*)d_in[0];
    const int*   context = (const int*)d_in[1];
    const float* V       = (const float*)d_in[2];
    const float* U       = (const float*)d_in[3];
    const float* vb      = (const float*)d_in[4];
    const float* ub      = (const float*)d_in[5];
    const float* comat   = (const float*)d_in[6];
    float* out = (float*)d_out;

    const int batch = in_sizes[0];

    // d_out is poisoned (0xAA) before every timed launch — zero it on-stream.
    hipMemsetAsync(out, 0, sizeof(float), stream);

    dim3 grid(1024), block(256);
    glove_kernel<<<grid, block, 0, stream>>>(center, context, V, U, vb, ub,
                                             comat, out, batch);
}

// Round 2
// 529.609 us; speedup vs baseline: 1.0094x; 1.0094x over previous
//
#include <hip/hip_runtime.h>

#define VOCAB 10000
#define EMBED 300
#define NBLOCKS 4096

// 16-lane sub-groups: each group handles one batch element per iteration.
// Row = 300 floats = 75 float4; lane l covers float4 idx = l + 16k, k=0..4
// (idx<75 masks lanes 11..15 on k=4).
__global__ __launch_bounds__(256) void glove_kernel(
    const int* __restrict__ center, const int* __restrict__ context,
    const float* __restrict__ V, const float* __restrict__ U,
    const float* __restrict__ vb, const float* __restrict__ ub,
    const float* __restrict__ comat, float* __restrict__ partials, int batch)
{
    const int lane16 = threadIdx.x & 15;
    const int group  = threadIdx.x >> 4;
    const int gpb    = blockDim.x >> 4;
    const int gid    = blockIdx.x * gpb + group;
    const int ngroups = gridDim.x * gpb;

    float total = 0.f;
    for (int b = gid; b < batch; b += ngroups) {
        const int i = center[b];
        const int j = context[b];
        // Hoist comat load: all 16 lanes load the same element (broadcast,
        // one line per group) so its HBM-miss latency overlaps the dot.
        const float x = comat[(size_t)i * VOCAB + j];
        const float4* __restrict__ Vrow = (const float4*)(V + (size_t)i * EMBED);
        const float4* __restrict__ Urow = (const float4*)(U + (size_t)j * EMBED);
        float dot = 0.f;
#pragma unroll
        for (int k = 0; k < 5; ++k) {
            const int idx = lane16 + 16 * k;
            if (idx < 75) {
                float4 a = Vrow[idx];
                float4 c = Urow[idx];
                dot = fmaf(a.x, c.x, dot);
                dot = fmaf(a.y, c.y, dot);
                dot = fmaf(a.z, c.z, dot);
                dot = fmaf(a.w, c.w, dot);
            }
        }
        // reduce within the 16-lane group
#pragma unroll
        for (int off = 8; off > 0; off >>= 1)
            dot += __shfl_down(dot, off, 16);
        if (lane16 == 0) {
            const float w = (x < 100.0f) ? __powf(x * 0.01f, 0.75f) : 1.0f;
            const float r = dot + vb[i] + ub[j] - __logf(x);
            total = fmaf(w * r, r, total);
        }
    }

    // wave-level reduce (width 64), then cross-wave via LDS, one partial/block
#pragma unroll
    for (int off = 32; off > 0; off >>= 1)
        total += __shfl_down(total, off, 64);

    __shared__ float smem[4];
    const int wave = threadIdx.x >> 6;
    const int lane = threadIdx.x & 63;
    if (lane == 0) smem[wave] = total;
    __syncthreads();
    if (threadIdx.x == 0)
        partials[blockIdx.x] = smem[0] + smem[1] + smem[2] + smem[3];
}

// Single-block final reduction: sums NBLOCKS partials, writes out[0].
// Writing (not accumulating) means no memset of d_out is needed.
__global__ __launch_bounds__(256) void reduce_kernel(
    const float* __restrict__ partials, float* __restrict__ out, int n)
{
    float s = 0.f;
    for (int k = threadIdx.x; k < n; k += 256)
        s += partials[k];
#pragma unroll
    for (int off = 32; off > 0; off >>= 1)
        s += __shfl_down(s, off, 64);

    __shared__ float smem[4];
    const int wave = threadIdx.x >> 6;
    const int lane = threadIdx.x & 63;
    if (lane == 0) smem[wave] = s;
    __syncthreads();
    if (threadIdx.x == 0)
        out[0] = smem[0] + smem[1] + smem[2] + smem[3];
}

extern "C" void kernel_launch(void* const* d_in, const int* in_sizes, int n_in,
                              void* d_out, int out_size, void* d_ws, size_t ws_size,
                              hipStream_t stream) {
    const int*   center  = (const int*)d_in[0];
    const int*   context = (const int*)d_in[1];
    const float* V       = (const float*)d_in[2];
    const float* U       = (const float*)d_in[3];
    const float* vb      = (const float*)d_in[4];
    const float* ub      = (const float*)d_in[5];
    const float* comat   = (const float*)d_in[6];
    float* out      = (float*)d_out;
    float* partials = (float*)d_ws;   // NBLOCKS floats of scratch

    const int batch = in_sizes[0];

    glove_kernel<<<dim3(NBLOCKS), dim3(256), 0, stream>>>(
        center, context, V, U, vb, ub, comat, partials, batch);
    reduce_kernel<<<dim3(1), dim3(256), 0, stream>>>(partials, out, NBLOCKS);
}

// Round 3
// 498.376 us; speedup vs baseline: 1.0727x; 1.0627x over previous
//
#include <hip/hip_runtime.h>

#define VOCAB 10000
#define EMBED 300
#define EMBED_PAD 320            // bf16 row padded to 640 B (line-aligned)
#define NBLOCKS 4096

// d_ws layout: [0, 16KB) partials (4096 floats); then Vb, Ub bf16 rows.
#define WS_PART_BYTES 16384
#define MAT_ELEMS (VOCAB * EMBED_PAD)   // 3.2M bf16 per matrix

__device__ __forceinline__ unsigned short f32_to_bf16_rne(float f) {
    unsigned int u = __builtin_bit_cast(unsigned int, f);
    u += 0x7fffu + ((u >> 16) & 1u);    // round-to-nearest-even
    return (unsigned short)(u >> 16);
}
__device__ __forceinline__ float bf16_lo(unsigned int u) {  // low 16 bits
    return __builtin_bit_cast(float, u << 16);
}
__device__ __forceinline__ float bf16_hi(unsigned int u) {  // high 16 bits
    return __builtin_bit_cast(float, u & 0xffff0000u);
}

// Pre-pass: V,U fp32 [10000x300] -> bf16 [10000x320] (pad = 0).
// One thread per 4-element output chunk: 2 * 10000 * 80 chunks.
__global__ __launch_bounds__(256) void convert_kernel(
    const float* __restrict__ V, const float* __restrict__ U,
    unsigned short* __restrict__ Vb, unsigned short* __restrict__ Ub)
{
    const int t = blockIdx.x * blockDim.x + threadIdx.x;
    const int total = 2 * VOCAB * (EMBED_PAD / 4);
    if (t >= total) return;
    const int m = t / (VOCAB * (EMBED_PAD / 4));
    const int rc = t - m * (VOCAB * (EMBED_PAD / 4));
    const int r = rc / (EMBED_PAD / 4);
    const int c = rc - r * (EMBED_PAD / 4);

    const float* src = (m ? U : V) + (size_t)r * EMBED + 4 * c;
    unsigned short* dst = (m ? Ub : Vb) + (size_t)r * EMBED_PAD + 4 * c;

    ushort4 o;
    if (c < EMBED / 4) {   // EMBED=300 divisible by 4 -> full float4 in-bounds
        float4 f = *(const float4*)src;
        o.x = f32_to_bf16_rne(f.x);
        o.y = f32_to_bf16_rne(f.y);
        o.z = f32_to_bf16_rne(f.z);
        o.w = f32_to_bf16_rne(f.w);
    } else {
        o = ushort4{0, 0, 0, 0};
    }
    *(ushort4*)dst = o;
}

// 16-lane sub-groups: one batch element per group-iteration.
// bf16 row = 40 x 16B chunks; lane l covers chunk l + 16k, k=0..2 (idx<40).
__global__ __launch_bounds__(256) void glove_kernel(
    const int* __restrict__ center, const int* __restrict__ context,
    const unsigned short* __restrict__ Vb, const unsigned short* __restrict__ Ub,
    const float* __restrict__ vb, const float* __restrict__ ub,
    const float* __restrict__ comat, float* __restrict__ partials, int batch)
{
    const int lane16 = threadIdx.x & 15;
    const int group  = threadIdx.x >> 4;
    const int gpb    = blockDim.x >> 4;
    const int gid    = blockIdx.x * gpb + group;
    const int ngroups = gridDim.x * gpb;

    float total = 0.f;
    for (int b = gid; b < batch; b += ngroups) {
        const int i = center[b];
        const int j = context[b];
        // comat load hoisted: broadcast within group, overlaps the dot.
        const float x = comat[(size_t)i * VOCAB + j];
        const uint4* __restrict__ Vrow = (const uint4*)(Vb + (size_t)i * EMBED_PAD);
        const uint4* __restrict__ Urow = (const uint4*)(Ub + (size_t)j * EMBED_PAD);
        float dot = 0.f;
#pragma unroll
        for (int k = 0; k < 3; ++k) {
            const int idx = lane16 + 16 * k;
            if (idx < EMBED_PAD * 2 / 16) {   // 40 chunks
                uint4 a = Vrow[idx];
                uint4 c = Urow[idx];
                dot = fmaf(bf16_lo(a.x), bf16_lo(c.x), dot);
                dot = fmaf(bf16_hi(a.x), bf16_hi(c.x), dot);
                dot = fmaf(bf16_lo(a.y), bf16_lo(c.y), dot);
                dot = fmaf(bf16_hi(a.y), bf16_hi(c.y), dot);
                dot = fmaf(bf16_lo(a.z), bf16_lo(c.z), dot);
                dot = fmaf(bf16_hi(a.z), bf16_hi(c.z), dot);
                dot = fmaf(bf16_lo(a.w), bf16_lo(c.w), dot);
                dot = fmaf(bf16_hi(a.w), bf16_hi(c.w), dot);
            }
        }
#pragma unroll
        for (int off = 8; off > 0; off >>= 1)
            dot += __shfl_down(dot, off, 16);
        if (lane16 == 0) {
            const float w = (x < 100.0f) ? __powf(x * 0.01f, 0.75f) : 1.0f;
            const float r = dot + vb[i] + ub[j] - __logf(x);
            total = fmaf(w * r, r, total);
        }
    }

#pragma unroll
    for (int off = 32; off > 0; off >>= 1)
        total += __shfl_down(total, off, 64);

    __shared__ float smem[4];
    const int wave = threadIdx.x >> 6;
    const int lane = threadIdx.x & 63;
    if (lane == 0) smem[wave] = total;
    __syncthreads();
    if (threadIdx.x == 0)
        partials[blockIdx.x] = smem[0] + smem[1] + smem[2] + smem[3];
}

__global__ __launch_bounds__(256) void reduce_kernel(
    const float* __restrict__ partials, float* __restrict__ out, int n)
{
    float s = 0.f;
    for (int k = threadIdx.x; k < n; k += 256)
        s += partials[k];
#pragma unroll
    for (int off = 32; off > 0; off >>= 1)
        s += __shfl_down(s, off, 64);

    __shared__ float smem[4];
    const int wave = threadIdx.x >> 6;
    const int lane = threadIdx.x & 63;
    if (lane == 0) smem[wave] = s;
    __syncthreads();
    if (threadIdx.x == 0)
        out[0] = smem[0] + smem[1] + smem[2] + smem[3];
}

extern "C" void kernel_launch(void* const* d_in, const int* in_sizes, int n_in,
                              void* d_out, int out_size, void* d_ws, size_t ws_size,
                              hipStream_t stream) {
    const int*   center  = (const int*)d_in[0];
    const int*   context = (const int*)d_in[1];
    const float* V       = (const float*)d_in[2];
    const float* U       = (const float*)d_in[3];
    const float* vb      = (const float*)d_in[4];
    const float* ub      = (const float*)d_in[5];
    const float* comat   = (const float*)d_in[6];
    float* out = (float*)d_out;

    float*          partials = (float*)d_ws;
    unsigned short* Vb = (unsigned short*)((char*)d_ws + WS_PART_BYTES);
    unsigned short* Ub = Vb + MAT_ELEMS;

    const int batch = in_sizes[0];

    const int conv_threads = 2 * VOCAB * (EMBED_PAD / 4);
    convert_kernel<<<dim3((conv_threads + 255) / 256), dim3(256), 0, stream>>>(
        V, U, Vb, Ub);
    glove_kernel<<<dim3(NBLOCKS), dim3(256), 0, stream>>>(
        center, context, Vb, Ub, vb, ub, comat, partials, batch);
    reduce_kernel<<<dim3(1), dim3(256), 0, stream>>>(partials, out, NBLOCKS);
}